// Round 3
// baseline (709.734 us; speedup 1.0000x reference)
//
#include <hip/hip_runtime.h>
#include <hip/hip_bf16.h>
#include <math.h>

#define N_NODES 50000
#define N_EDGES 1600000
#define N_FEAT  256
#define HIDDEN  32
#define N_CLASS 64
#define NBUCK   391      // ceil(50000 / 128) nodes-per-bucket = 128
#define EPB     7168     // edges per block in bin_edges
#define CAP     6144     // max staged edges per bucket in build_csr (avg 4096)

// ---------------- CSR build via bucket binning (unchanged from R2) ----------------

__global__ __launch_bounds__(256) void bucket_count(const int* __restrict__ dst,
                                                    int* __restrict__ gcnt) {
  __shared__ int h[NBUCK];
  for (int i = threadIdx.x; i < NBUCK; i += 256) h[i] = 0;
  __syncthreads();
  int base = blockIdx.x * 8192;
  for (int i = threadIdx.x; i < 8192; i += 256) {
    int e = base + i;
    if (e < N_EDGES) atomicAdd(&h[dst[e] >> 7], 1);
  }
  __syncthreads();
  for (int i = threadIdx.x; i < NBUCK; i += 256)
    if (h[i]) atomicAdd(&gcnt[i], h[i]);
}

__global__ __launch_bounds__(512) void bucket_scan(const int* __restrict__ gcnt,
                                                   int* __restrict__ goff) {
  __shared__ int s[512];
  int t = threadIdx.x;
  int v = (t < NBUCK) ? gcnt[t] : 0;
  s[t] = v;
  __syncthreads();
  for (int off = 1; off < 512; off <<= 1) {
    int u = (t >= off) ? s[t - off] : 0;
    __syncthreads();
    s[t] += u;
    __syncthreads();
  }
  if (t <= NBUCK) goff[t] = (t == 0) ? 0 : s[t - 1];
}

__global__ __launch_bounds__(256) void bin_edges(const int* __restrict__ src,
                                                 const int* __restrict__ dst,
                                                 const float* __restrict__ val,
                                                 const int* __restrict__ goff,
                                                 int* __restrict__ bcur,
                                                 int2* __restrict__ st) {
  __shared__ int h[NBUCK];
  __shared__ int lstart[NBUCK];
  __shared__ int lcur[NBUCK];
  __shared__ int gbase[NBUCK];
  __shared__ int2 stage[EPB];
  int t = threadIdx.x;
  for (int i = t; i < NBUCK; i += 256) { h[i] = 0; lcur[i] = 0; }
  __syncthreads();
  int base = blockIdx.x * EPB;
  int nloc = min(EPB, N_EDGES - base);
  for (int i = t; i < nloc; i += 256) atomicAdd(&h[dst[base + i] >> 7], 1);
  __syncthreads();
  if (t < 64) {
    int loc[7];
    int s0 = 0;
#pragma unroll
    for (int i = 0; i < 7; ++i) {
      int b = t * 7 + i;
      int c = (b < NBUCK) ? h[b] : 0;
      loc[i] = s0; s0 += c;
    }
    int run = s0;
#pragma unroll
    for (int off = 1; off < 64; off <<= 1) {
      int u = __shfl_up(run, off);
      if (t >= off) run += u;
    }
    int excl = run - s0;
#pragma unroll
    for (int i = 0; i < 7; ++i) {
      int b = t * 7 + i;
      if (b < NBUCK) lstart[b] = excl + loc[i];
    }
  }
  __syncthreads();
  for (int i = t; i < NBUCK; i += 256) {
    int c = h[i];
    gbase[i] = c ? (goff[i] + atomicAdd(&bcur[i], c)) : 0;
  }
  __syncthreads();
  for (int i = t; i < nloc; i += 256) {
    int e = base + i;
    int d = dst[e];
    int b = d >> 7;
    int pos = lstart[b] + atomicAdd(&lcur[b], 1);
    stage[pos] = make_int2((src[e] << 16) | d, __float_as_int(val[e]));
  }
  __syncthreads();
  for (int i = t; i < nloc; i += 256) {
    int2 v = stage[i];
    int b = (v.x & 0xffff) >> 7;
    st[gbase[b] + (i - lstart[b])] = v;
  }
}

__global__ __launch_bounds__(256) void build_csr(const int* __restrict__ goff,
                                                 const int2* __restrict__ st,
                                                 int* __restrict__ rp,
                                                 int2* __restrict__ ep) {
  __shared__ int2 stage[CAP];
  __shared__ int lh[128], lstart[128], lcur[128];
  int b = blockIdx.x, t = threadIdx.x;
  int beg = goff[b], end = goff[b + 1];
  int n = min(end - beg, CAP);
  for (int i = t; i < 128; i += 256) { lh[i] = 0; lcur[i] = 0; }
  __syncthreads();
  for (int i = t; i < n; i += 256) {
    int2 v = st[beg + i];
    stage[i] = v;
    atomicAdd(&lh[v.x & 127], 1);
  }
  __syncthreads();
  if (t < 64) {
    int a0 = lh[2 * t], a1 = lh[2 * t + 1];
    int s0 = a0 + a1;
    int run = s0;
#pragma unroll
    for (int off = 1; off < 64; off <<= 1) {
      int u = __shfl_up(run, off);
      if (t >= off) run += u;
    }
    int excl = run - s0;
    lstart[2 * t] = excl;
    lstart[2 * t + 1] = excl + a0;
  }
  __syncthreads();
  int nodebase = b * 128;
  int nn = min(128, N_NODES - nodebase);
  for (int i = t; i < nn; i += 256) rp[nodebase + i] = beg + lstart[i];
  if (b == NBUCK - 1 && t == 0) rp[N_NODES] = N_EDGES;
  for (int i = t; i < n; i += 256) {
    int2 v = stage[i];
    int d = v.x & 127;
    int pos = lstart[d] + atomicAdd(&lcur[d], 1);
    ep[beg + pos] = make_int2((int)(((unsigned)v.x) >> 16), v.y);
  }
}

// ---------------- MLP + softmax -> p0 (4-way K-split, 12 waves/CU) ----------------
// block = 256 threads / 64 nodes. Wave w: partial h over feats [64w,64w+64).
// LDS: hs[4][64][33] @0 (8448 f), hfull[64][33] @8448 (2112 f); ps reuses @0.

__global__ __launch_bounds__(256) void mlp_kernel(const float* __restrict__ x,
                                                  const float* __restrict__ W1,
                                                  const float* __restrict__ b1,
                                                  const float* __restrict__ W2,
                                                  const float* __restrict__ b2,
                                                  float* __restrict__ P) {
  __shared__ float lds[10560];
  float* hs = lds;
  float* hfull = lds + 8448;
  float* ps = lds;

  int t = threadIdx.x, w = t >> 6, l = t & 63;
  int n0 = blockIdx.x * 64;
  int node = n0 + l;

  float h[HIDDEN];
#pragma unroll
  for (int j = 0; j < HIDDEN; ++j) h[j] = 0.f;

  if (node < N_NODES) {
    const float4* xp = (const float4*)(x + (size_t)node * N_FEAT + w * 64);
#pragma unroll 2
    for (int ch = 0; ch < 16; ++ch) {
      float4 xv = xp[ch];
      const float* wr = W1 + (w * 64 + ch * 4) * HIDDEN;  // wave-uniform
#pragma unroll
      for (int j = 0; j < HIDDEN; ++j) h[j] = fmaf(xv.x, wr[j], h[j]);
#pragma unroll
      for (int j = 0; j < HIDDEN; ++j) h[j] = fmaf(xv.y, wr[HIDDEN + j], h[j]);
#pragma unroll
      for (int j = 0; j < HIDDEN; ++j) h[j] = fmaf(xv.z, wr[2 * HIDDEN + j], h[j]);
#pragma unroll
      for (int j = 0; j < HIDDEN; ++j) h[j] = fmaf(xv.w, wr[3 * HIDDEN + j], h[j]);
    }
  }
#pragma unroll
  for (int j = 0; j < HIDDEN; ++j) hs[w * 2112 + l * 33 + j] = h[j];
  __syncthreads();

  // reduce partials + bias + ReLU: thread t -> node n=t>>2, j-range (t&3)*8..+8
  {
    int n = t >> 2, j0 = (t & 3) * 8;
#pragma unroll
    for (int i = 0; i < 8; ++i) {
      int j = j0 + i;
      float v = hs[n * 33 + j] + hs[2112 + n * 33 + j] +
                hs[4224 + n * 33 + j] + hs[6336 + n * 33 + j];
      hfull[n * 33 + j] = fmaxf(v + b1[j], 0.f);
    }
  }
  __syncthreads();

  // layer 2: wave w -> classes [16w,16w+16); lane l = node-local index
  float p[16];
#pragma unroll
  for (int c = 0; c < 16; ++c) p[c] = b2[16 * w + c];
  for (int kk = 0; kk < HIDDEN; ++kk) {
    float hk = hfull[l * 33 + kk];
    const float* w2r = W2 + kk * N_CLASS + 16 * w;  // wave-uniform
#pragma unroll
    for (int c = 0; c < 16; ++c) p[c] = fmaf(hk, w2r[c], p[c]);
  }
#pragma unroll
  for (int c = 0; c < 16; ++c) ps[l * 65 + 16 * w + c] = p[c];
  __syncthreads();

  // softmax: thread t -> node n=t>>2, class-chunk (t&3)*16
  {
    int n = t >> 2, ck = (t & 3) * 16;
    float q[16];
    float m = -1e30f;
#pragma unroll
    for (int i = 0; i < 16; ++i) { q[i] = ps[n * 65 + ck + i]; m = fmaxf(m, q[i]); }
    m = fmaxf(m, __shfl_xor(m, 1));
    m = fmaxf(m, __shfl_xor(m, 2));
    float s = 0.f;
#pragma unroll
    for (int i = 0; i < 16; ++i) { q[i] = expf(q[i] - m); s += q[i]; }
    s += __shfl_xor(s, 1);
    s += __shfl_xor(s, 2);
    float inv = 1.f / s;
    int gn = n0 + n;
    if (gn < N_NODES) {
      float4* op = (float4*)(P + (size_t)gn * N_CLASS + ck);
#pragma unroll
      for (int i4 = 0; i4 < 4; ++i4)
        op[i4] = make_float4(q[i4 * 4] * inv, q[i4 * 4 + 1] * inv,
                             q[i4 * 4 + 2] * inv, q[i4 * 4 + 3] * inv);
    }
  }
}

// ---------------- SpMM + 0.5*tanh, channel-quartered with XCD affinity --------
// blockIdx -> (quarter q, node-group) s.t. q = (blockIdx%8)>>1: one XCD pair
// gathers only its 3.2 MB channel slice -> fits 4 MB per-XCD L2.
// Wave = one (node, quarter): 16 channel-lanes x 4 edge-subgroups.

__global__ __launch_bounds__(256) void spmm_q(const int* __restrict__ rp,
                                              const int2* __restrict__ ep,
                                              const float* __restrict__ pin,
                                              float* __restrict__ pout) {
  int i = blockIdx.x;
  int x3 = i & 7;
  int q = x3 >> 1;
  int ng = (i >> 3) * 2 + (x3 & 1);
  int wv = threadIdx.x >> 6, lane = threadIdx.x & 63;
  int node = ng * 4 + wv;
  int c = lane & 15, g = lane >> 4;
  int beg = rp[node], end = rp[node + 1];
  const float* pq = pin + q * 16 + c;
  float acc = 0.f;
  for (int base = beg; base < end; base += 64) {
    int idx = base + lane;
    int2 epk = (idx < end) ? ep[idx] : make_int2(0, 0);
    int cnt = min(64, end - base);
#pragma unroll 4
    for (int j = g; j < cnt; j += 4) {
      int   sj = __shfl(epk.x, j);
      float vj = __int_as_float(__shfl(epk.y, j));
      acc = fmaf(vj, pq[(size_t)sj << 6], acc);
    }
  }
  acc += __shfl_xor(acc, 16);
  acc += __shfl_xor(acc, 32);
  if (g == 0) pout[((size_t)node << 6) + q * 16 + c] = 0.5f * tanhf(acc);
}

// ---------------- final row softmax ----------------
// wave = 4 nodes, 16 lanes/node, float4 per lane.

__global__ __launch_bounds__(256) void softmax_kernel(const float* __restrict__ pin,
                                                      float* __restrict__ out) {
  int t = threadIdx.x;
  int node = blockIdx.x * 16 + (t >> 4);
  int c = t & 15;
  float4 v = ((const float4*)(pin + (size_t)node * N_CLASS))[c];
  float m = fmaxf(fmaxf(v.x, v.y), fmaxf(v.z, v.w));
#pragma unroll
  for (int off = 1; off <= 8; off <<= 1) m = fmaxf(m, __shfl_xor(m, off));
  float4 e;
  e.x = expf(v.x - m); e.y = expf(v.y - m);
  e.z = expf(v.z - m); e.w = expf(v.w - m);
  float s = e.x + e.y + e.z + e.w;
#pragma unroll
  for (int off = 1; off <= 8; off <<= 1) s += __shfl_xor(s, off);
  float inv = 1.f / s;
  ((float4*)(out + (size_t)node * N_CLASS))[c] =
      make_float4(e.x * inv, e.y * inv, e.z * inv, e.w * inv);
}

// ---------------- launch ----------------

extern "C" void kernel_launch(void* const* d_in, const int* in_sizes, int n_in,
                              void* d_out, int out_size, void* d_ws, size_t ws_size,
                              hipStream_t stream) {
  const float* x    = (const float*)d_in[0];
  const int*   esrc = (const int*)d_in[1];
  const int*   edst = (const int*)d_in[2];
  const float* evl  = (const float*)d_in[3];
  const float* W1   = (const float*)d_in[4];
  const float* b1   = (const float*)d_in[5];
  const float* W2   = (const float*)d_in[6];
  const float* b2   = (const float*)d_in[7];
  float* out = (float*)d_out;

  char* ws = (char*)d_ws;
  float* Pa  = (float*)(ws);                        // 12.8 MB (aliases st)
  float* Pb  = (float*)(ws + 12800000);             // 12.8 MB
  int2*  ep  = (int2*) (ws + 25600000);             // 12.8 MB
  int2*  st  = (int2*) (ws);                        // staging, dead before mlp writes Pa
  int*   gcnt = (int*)(ws + 38400000);
  int*   bcur = (int*)(ws + 38401600);
  int*   goff = (int*)(ws + 38403200);
  int*   rp   = (int*)(ws + 38404800);

  hipMemsetAsync(gcnt, 0, 800 * sizeof(int), stream);  // gcnt + bcur

  bucket_count<<<196, 256, 0, stream>>>(edst, gcnt);
  bucket_scan<<<1, 512, 0, stream>>>(gcnt, goff);
  bin_edges<<<224, 256, 0, stream>>>(esrc, edst, evl, goff, bcur, st);
  build_csr<<<NBUCK, 256, 0, stream>>>(goff, st, rp, ep);

  mlp_kernel<<<782, 256, 0, stream>>>(x, W1, b1, W2, b2, Pa);

  spmm_q<<<50000, 256, 0, stream>>>(rp, ep, Pa, Pb);
  spmm_q<<<50000, 256, 0, stream>>>(rp, ep, Pb, Pa);
  spmm_q<<<50000, 256, 0, stream>>>(rp, ep, Pa, Pb);
  spmm_q<<<50000, 256, 0, stream>>>(rp, ep, Pb, Pa);

  softmax_kernel<<<3125, 256, 0, stream>>>(Pa, out);
}